// Round 1
// baseline (33094.406 us; speedup 1.0000x reference)
//
#include <hip/hip_runtime.h>

// Problem constants (B,T,S,L,D_IN,OUT,W = 256,512,256,36,8,10,256)
#define Tt   512
#define Ll   36
#define DIN  8
#define OUTd 10

typedef __attribute__((ext_vector_type(8))) short short8;
typedef __attribute__((ext_vector_type(4))) float f32x4;

__device__ __forceinline__ unsigned short f2bf(float f) {
    union { float f; unsigned int u; } v; v.f = f;
    unsigned int r = v.u + 0x7fffu + ((v.u >> 16) & 1u);   // RNE
    return (unsigned short)(r >> 16);
}
__device__ __forceinline__ float bf2f(unsigned short u) {
    union { unsigned int u; float f; } v; v.u = ((unsigned int)u) << 16;
    return v.f;
}
__device__ __forceinline__ float sp_f(float x) {      // jax.nn.softplus
    return fmaxf(x, 0.f) + __logf(1.f + __expf(-fabsf(x)));
}
__device__ __forceinline__ float tanh_f(float x) {
    float e = __expf(2.f * x);
    return 1.f - 2.f / (e + 1.f);
}

// ---- agent-scope (sc1 / LLC-coherent) helpers: cross-XCD-safe ----
__device__ __forceinline__ unsigned long long ldg64(const void* p) {
    return __hip_atomic_load((const unsigned long long*)p, __ATOMIC_RELAXED, __HIP_MEMORY_SCOPE_AGENT);
}
__device__ __forceinline__ void stg64(void* p, unsigned long long v) {
    __hip_atomic_store((unsigned long long*)p, v, __ATOMIC_RELAXED, __HIP_MEMORY_SCOPE_AGENT);
}
__device__ __forceinline__ void stgf(float* p, float v) {
    __hip_atomic_store(p, v, __ATOMIC_RELAXED, __HIP_MEMORY_SCOPE_AGENT);
}
union U64F2 { unsigned long long u; float f[2]; unsigned short s[4]; };
union S8U   { unsigned long long u[2]; short8 v; };

// ---- LDS layout ----
// GScr: h / z1 / z2 (z2 overwrites hh/hl) staging for the per-block MLP, 64 rows x 264 stride
// CScr: W3 double-buffer + per-step scratch (overlaps GScr; ordering enforced by syncthreads)
struct GScr { short hh[64*264], hl[64*264], z1h[64*264], z1l[64*264]; };           // 135168 B
struct CScr { short w3s[2][18432]; float lss[64*Ll]; float ml[64*148]; float b3s[144]; }; // 121408 B
struct IScr { float x0s[32][DIN]; float h1[32*257]; float h2[32*257]; };            // 66816 B
union  Scr  { GScr g; CScr c; IScr in; };

// ---- tree grid barrier: 8 monotone group counters -> super counter -> release word ----
__device__ __forceinline__ void gbar(int* bar, int gen) {
    __syncthreads();
    if (threadIdx.x == 0) {
        const int g = blockIdx.x & 7;
        int old = __hip_atomic_fetch_add(bar + g * 32, 1, __ATOMIC_RELAXED, __HIP_MEMORY_SCOPE_AGENT);
        if (old == gen * 32 - 1) {                       // last block of this group
            int o2 = __hip_atomic_fetch_add(bar + 8 * 32, 1, __ATOMIC_RELAXED, __HIP_MEMORY_SCOPE_AGENT);
            if (o2 == gen * 8 - 1)                       // last group overall -> release
                __hip_atomic_store(bar + 9 * 32, gen, __ATOMIC_RELAXED, __HIP_MEMORY_SCOPE_AGENT);
        }
        while (__hip_atomic_load(bar + 9 * 32, __ATOMIC_RELAXED, __HIP_MEMORY_SCOPE_AGENT) < gen)
            __builtin_amdgcn_s_sleep(4);
    }
    __syncthreads();
}

__device__ __forceinline__ void cast_quad(const float* src, unsigned short* dh,
                                          unsigned short* dl, long u) {
    f32x4 f = *(const f32x4*)(src + u * 4);
    U64F2 H, L;
#pragma unroll
    for (int q = 0; q < 4; ++q) {
        float v = f[q];
        unsigned short hi = f2bf(v);
        H.s[q] = hi;
        L.s[q] = f2bf(v - bf2f(hi));
    }
    stg64(dh + u * 4, H.u);
    stg64(dl + u * 4, L.u);
}

// one MLP stage: Z = softplus(A @ B^T + bias), A/Z are LDS [64][264] hi/lo bf16,
// B is global [256][256] hi/lo bf16. n-slice wave decomposition (wave wv owns 64 n-cols),
// rb loop over 4 row-blocks of 16. B-frags hoisted so W is read once per block per stage.
#define MLP_STAGE(Ah, Al, Bh, Bl, BIAS, Zh, Zl) do {                                        \
    f32x4 acc_[4][4];                                                                        \
    _Pragma("unroll")                                                                        \
    for (int rb_ = 0; rb_ < 4; ++rb_) {                                                      \
      _Pragma("unroll")                                                                      \
      for (int j_ = 0; j_ < 4; ++j_) acc_[rb_][j_] = zero4;                                  \
    }                                                                                        \
    for (int k0_ = 0; k0_ < 256; k0_ += 32) {                                                \
      short8 bh_[4], bl_[4];                                                                 \
      _Pragma("unroll")                                                                      \
      for (int j_ = 0; j_ < 4; ++j_) {                                                       \
        int n_ = (4 * wv + j_) * 16 + l15;                                                   \
        bh_[j_] = *(const short8*)(const void*)((Bh) + n_ * 256 + k0_ + quad * 8);           \
        bl_[j_] = *(const short8*)(const void*)((Bl) + n_ * 256 + k0_ + quad * 8);           \
      }                                                                                      \
      _Pragma("unroll")                                                                      \
      for (int rb_ = 0; rb_ < 4; ++rb_) {                                                    \
        short8 ah_ = *(const short8*)(const void*)&(Ah)[(rb_ * 16 + l15) * 264 + k0_ + quad * 8]; \
        short8 al_ = *(const short8*)(const void*)&(Al)[(rb_ * 16 + l15) * 264 + k0_ + quad * 8]; \
        _Pragma("unroll")                                                                    \
        for (int j_ = 0; j_ < 4; ++j_) {                                                     \
          acc_[rb_][j_] = __builtin_amdgcn_mfma_f32_16x16x32_bf16(ah_, bh_[j_], acc_[rb_][j_], 0, 0, 0); \
          acc_[rb_][j_] = __builtin_amdgcn_mfma_f32_16x16x32_bf16(ah_, bl_[j_], acc_[rb_][j_], 0, 0, 0); \
          acc_[rb_][j_] = __builtin_amdgcn_mfma_f32_16x16x32_bf16(al_, bh_[j_], acc_[rb_][j_], 0, 0, 0); \
        }                                                                                    \
      }                                                                                      \
    }                                                                                        \
    _Pragma("unroll")                                                                        \
    for (int rb_ = 0; rb_ < 4; ++rb_) {                                                      \
      _Pragma("unroll")                                                                      \
      for (int j_ = 0; j_ < 4; ++j_) {                                                       \
        int n_ = (4 * wv + j_) * 16 + l15;                                                   \
        float bs_ = (BIAS)[n_];                                                              \
        _Pragma("unroll")                                                                    \
        for (int r_ = 0; r_ < 4; ++r_) {                                                     \
          int row_ = rb_ * 16 + quad * 4 + r_;                                               \
          float v_ = sp_f(acc_[rb_][j_][r_] + bs_);                                          \
          unsigned short hi_ = f2bf(v_);                                                     \
          (Zh)[row_ * 264 + n_] = (short)hi_;                                                \
          (Zl)[row_ * 264 + n_] = (short)f2bf(v_ - bf2f(hi_));                               \
        }                                                                                    \
      }                                                                                      \
    }                                                                                        \
  } while (0)

__global__ __launch_bounds__(256, 1) void rde_fused(
    const float* __restrict__ x0, const float* __restrict__ logsigs,
    const float* __restrict__ iW1, const float* __restrict__ ib1,
    const float* __restrict__ iW2, const float* __restrict__ ib2,
    const float* __restrict__ iW3, const float* __restrict__ ib3,
    const float* __restrict__ vW1, const float* __restrict__ vb1,
    const float* __restrict__ vW2, const float* __restrict__ vb2,
    const float* __restrict__ vW3, const float* __restrict__ vb3,
    const float* __restrict__ roW, const float* __restrict__ rob,
    float* __restrict__ out,
    float* hA, float* hB,
    unsigned short* w1h, unsigned short* w1l,
    unsigned short* w2h, unsigned short* w2l,
    unsigned short* w3h, unsigned short* w3l, int* slots) {
    __shared__ Scr S;
    __shared__ float hloc[256];   // persistent h slice (64 rows x 4 s), exclusively owned, exact f32
    __shared__ float rtmp[44];    // readout partials (4 waves x 10 outputs)
    const int tid = threadIdx.x, blk = blockIdx.x;
    const int lane = tid & 63, wv = tid >> 6, quad = lane >> 4, l15 = lane & 15;
    // XCD-aware slot mapping: blk%8 ~ XCD; same-XCD blocks share only 8 W3 slices
    // (8 x 147 KB = 1.2 MB -> W3 + W1/W2 stay L2-resident per XCD). Bijective.
    const int nsl = (blk & 7) * 8 + ((blk >> 3) & 7);
    const int bch = blk >> 6;
    const int b0c = bch * 64, n0 = nsl * 144, s0 = nsl * 4;
    const f32x4 zero4 = {0.f, 0.f, 0.f, 0.f};
    int gen = 0;

    // ================= phase 0: init MLP (blk<8), W1/W2 cast (8..15), W3 cast (16..255) ======
    if (blk < 8) {
        IScr& I = S.in;
        const int b0 = blk * 32;
        I.x0s[tid >> 3][tid & 7] = x0[(b0 + (tid >> 3)) * DIN + (tid & 7)];
        __syncthreads();
        const int j = tid;
        {
            float w[DIN];
#pragma unroll
            for (int k = 0; k < DIN; ++k) w[k] = iW1[j * DIN + k];
            float bias = ib1[j];
            for (int r = 0; r < 32; ++r) {
                float acc = bias;
#pragma unroll
                for (int k = 0; k < DIN; ++k) acc += I.x0s[r][k] * w[k];
                I.h1[r * 257 + j] = sp_f(acc);
            }
        }
        __syncthreads();
        {
            float bias = ib2[j];
            for (int rb = 0; rb < 4; ++rb) {
                float a8[8];
#pragma unroll
                for (int rr = 0; rr < 8; ++rr) a8[rr] = bias;
                for (int k = 0; k < 256; ++k) {
                    float wvv = iW2[j * 256 + k];
#pragma unroll
                    for (int rr = 0; rr < 8; ++rr) a8[rr] += I.h1[(rb * 8 + rr) * 257 + k] * wvv;
                }
#pragma unroll
                for (int rr = 0; rr < 8; ++rr) I.h2[(rb * 8 + rr) * 257 + j] = sp_f(a8[rr]);
            }
        }
        __syncthreads();
        {
            float bias = ib3[j];
            for (int rb = 0; rb < 4; ++rb) {
                float a8[8];
#pragma unroll
                for (int rr = 0; rr < 8; ++rr) a8[rr] = bias;
                for (int k = 0; k < 256; ++k) {
                    float wvv = iW3[j * 256 + k];
#pragma unroll
                    for (int rr = 0; rr < 8; ++rr) a8[rr] += I.h2[(rb * 8 + rr) * 257 + k] * wvv;
                }
#pragma unroll
                for (int rr = 0; rr < 8; ++rr)
                    stgf(&hA[(b0 + rb * 8 + rr) * 256 + j], a8[rr]);   // publish h0 to LLC
            }
        }
    } else if (blk < 16) {
        const int idx = blk - 8;
        const float* src = (idx < 4) ? vW1 : vW2;
        unsigned short* dh = (idx < 4) ? w1h : w2h;
        unsigned short* dl = (idx < 4) ? w1l : w2l;
        const int part = idx & 3;
        for (int u = part * 4096 + tid; u < (part + 1) * 4096; u += 256)
            cast_quad(src, dh, dl, u);
    } else {
        for (long u = (long)(blk - 16) * 256 + tid; u < 589824; u += 240L * 256)
            cast_quad(vW3, w3h, w3l, u);
    }
    gbar(slots, ++gen);

    // load persistent h slice (h0) once — exact f32 accumulator
    if (tid < 64) {
        U64F2 a, b;
        a.u = ldg64(hA + (b0c + tid) * 256 + s0);
        b.u = ldg64(hA + (b0c + tid) * 256 + s0 + 2);
        hloc[tid * 4 + 0] = a.f[0]; hloc[tid * 4 + 1] = a.f[1];
        hloc[tid * 4 + 2] = b.f[0]; hloc[tid * 4 + 3] = b.f[1];
    }

    // ================= main scan: ONE grid barrier per step =================
    for (int t = 0; t < Tt; ++t) {
        GScr& G = S.g;
        const float* hsrc = (t & 1) ? hB : hA;
        float* hdst = (t & 1) ? hA : hB;

        // ---- gather h(t) rows [64 x 256] from LLC, split hi/lo into LDS ----
#pragma unroll 4
        for (int u = tid; u < 8192; u += 256) {
            int r = u >> 7, c = (u & 127) * 2;
            U64F2 vv; vv.u = ldg64(hsrc + (b0c + r) * 256 + c);
#pragma unroll
            for (int q = 0; q < 2; ++q) {
                float v = vv.f[q];
                unsigned short hi = f2bf(v);
                G.hh[r * 264 + c + q] = (short)hi;
                G.hl[r * 264 + c + q] = (short)f2bf(v - bf2f(hi));
            }
        }
        __syncthreads();

        // ---- readout partials for out[b0c+nsl, t, :] (lanes 0..9 of each wave, s-quarter wv) ----
        if (lane < OUTd) {
            const int o = lane;
            float acc = 0.f;
            const short* ph = &G.hh[nsl * 264 + wv * 64];
            const short* pl = &G.hl[nsl * 264 + wv * 64];
            const float* wp = roW + o * 256 + wv * 64;
            for (int s = 0; s < 64; s += 8) {
                short8 vh = *(const short8*)(const void*)(ph + s);
                short8 vl = *(const short8*)(const void*)(pl + s);
                f32x4 w0 = *(const f32x4*)(wp + s);
                f32x4 w1 = *(const f32x4*)(wp + s + 4);
#pragma unroll
                for (int q = 0; q < 4; ++q) {
                    acc += (bf2f((unsigned short)vh[q]) + bf2f((unsigned short)vl[q])) * w0[q];
                    acc += (bf2f((unsigned short)vh[q + 4]) + bf2f((unsigned short)vl[q + 4])) * w1[q];
                }
            }
            rtmp[wv * 10 + o] = acc;
        }

        // ---- stage 1: z1 = sp(h W1^T) ----
        MLP_STAGE(G.hh, G.hl, w1h, w1l, vb1, G.z1h, G.z1l);
        __syncthreads();

        // readout: combine wave partials, write out[:, t, :]
        if (tid < OUTd)
            out[((long)(b0c + nsl) * 513 + t) * OUTd + tid] =
                rob[tid] + rtmp[tid] + rtmp[10 + tid] + rtmp[20 + tid] + rtmp[30 + tid];

        // ---- stage 2: z2 = sp(z1 W2^T) -> back into hh/hl ----
        MLP_STAGE(G.z1h, G.z1l, w2h, w2l, vb2, G.hh, G.hl);
        __syncthreads();

        // ---- load z2 A-fragments into registers (before W3 staging overwrites LDS) ----
        S8U zh[8], zl[8];
        {
            const int rl = 16 * wv + l15;
#pragma unroll
            for (int kk = 0; kk < 8; ++kk) {
                zh[kk].v = *(const short8*)(const void*)&G.hh[rl * 264 + kk * 32 + quad * 8];
                zl[kk].v = *(const short8*)(const void*)&G.hl[rl * 264 + kk * 32 + quad * 8];
            }
        }
        __syncthreads();

        // ---- W3 phase: m = tanh(z2 W3^T + b3); h += einsum(m, ls) ----
        {
            CScr& C = S.c;
            for (int i = tid; i < 64 * Ll; i += 256) {
                int r = i / Ll, l = i - r * Ll;
                C.lss[i] = logsigs[((long)(b0c + r) * Tt + t) * Ll + l];
            }
            if (tid < 144) C.b3s[tid] = vb3[n0 + tid];
            // stage W3 chunk 0 (k 0..63), frag-contiguous layout
            for (int u = tid; u < 2304; u += 256) {
                int isLo = (u >= 1152) ? 1 : 0;
                int uu = u - isLo * 1152;
                int r = uu >> 3, p = uu & 7;
                const unsigned short* src = isLo ? w3l : w3h;
                short8 v = *(const short8*)(const void*)(src + (long)(n0 + r) * 256 + p * 8);
                int d = ((p >> 2) * 9 + (r >> 4)) * 64 + (p & 3) * 16 + (r & 15);
                *(short8*)(void*)(C.w3s[0] + isLo * 9216 + d * 8) = v;
            }
            __syncthreads();
            f32x4 acc[9];
#pragma unroll
            for (int nt = 0; nt < 9; ++nt) acc[nt] = zero4;
#pragma unroll
            for (int c4 = 0; c4 < 4; ++c4) {
                if (c4 < 3) {   // prefetch next W3 chunk into other buffer
                    for (int u = tid; u < 2304; u += 256) {
                        int isLo = (u >= 1152) ? 1 : 0;
                        int uu = u - isLo * 1152;
                        int r = uu >> 3, p = uu & 7;
                        const unsigned short* src = isLo ? w3l : w3h;
                        short8 v = *(const short8*)(const void*)(src + (long)(n0 + r) * 256 + (c4 + 1) * 64 + p * 8);
                        int d = ((p >> 2) * 9 + (r >> 4)) * 64 + (p & 3) * 16 + (r & 15);
                        *(short8*)(void*)(C.w3s[(c4 + 1) & 1] + isLo * 9216 + d * 8) = v;
                    }
                }
                const short* wb = C.w3s[c4 & 1];
#pragma unroll
                for (int sub = 0; sub < 2; ++sub) {
                    const int kk = c4 * 2 + sub;
#pragma unroll
                    for (int nt = 0; nt < 9; ++nt) {
                        const short* pp = wb + ((sub * 9 + nt) * 64 + lane) * 8;
                        short8 bh = *(const short8*)(const void*)pp;
                        short8 bl = *(const short8*)(const void*)(pp + 9216);
                        acc[nt] = __builtin_amdgcn_mfma_f32_16x16x32_bf16(zh[kk].v, bh, acc[nt], 0, 0, 0);
                        acc[nt] = __builtin_amdgcn_mfma_f32_16x16x32_bf16(zh[kk].v, bl, acc[nt], 0, 0, 0);
                        acc[nt] = __builtin_amdgcn_mfma_f32_16x16x32_bf16(zl[kk].v, bh, acc[nt], 0, 0, 0);
                    }
                }
                __syncthreads();
            }
            // epilogue: tanh -> ml
#pragma unroll
            for (int nt = 0; nt < 9; ++nt) {
                int nl = nt * 16 + l15;
                float bias = C.b3s[nl];
#pragma unroll
                for (int r = 0; r < 4; ++r) {
                    int row = 16 * wv + quad * 4 + r;
                    C.ml[row * 148 + nl] = tanh_f(acc[nt][r] + bias);
                }
            }
            __syncthreads();
            // l-contraction: each thread owns one (row, sr): hloc[tid] += dot36
            {
                int row = tid >> 2, sr = tid & 3;
                const f32x4* mp = (const f32x4*)(const void*)&C.ml[row * 148 + sr * 36];
                const f32x4* lp = (const f32x4*)(const void*)&C.lss[row * 36];
                float a = 0.f;
#pragma unroll
                for (int q = 0; q < 9; ++q) {
                    f32x4 m4 = mp[q], l4 = lp[q];
                    a += m4[0] * l4[0] + m4[1] * l4[1] + m4[2] * l4[2] + m4[3] * l4[3];
                }
                hloc[tid] += a;
            }
            __syncthreads();
            if (tid < 64) {   // publish h slice (exclusive owner) to the OTHER buffer
                U64F2 p0, p1;
                p0.f[0] = hloc[tid * 4 + 0]; p0.f[1] = hloc[tid * 4 + 1];
                p1.f[0] = hloc[tid * 4 + 2]; p1.f[1] = hloc[tid * 4 + 3];
                stg64(hdst + (b0c + tid) * 256 + s0, p0.u);
                stg64(hdst + (b0c + tid) * 256 + s0 + 2, p1.u);
            }
        }
        gbar(slots, ++gen);
    }

    // ---- final readout out[:, 512, :]  (h(512) is in hA since Tt is even) ----
    {
        float* fb = S.c.lss;   // reuse as f32 row buffer
        if (tid < 128) {
            U64F2 v; v.u = ldg64(hA + (long)(b0c + nsl) * 256 + tid * 2);
            fb[tid * 2] = v.f[0]; fb[tid * 2 + 1] = v.f[1];
        }
        __syncthreads();
        if (tid < OUTd) {
            float acc = rob[tid];
            const float* wp = roW + tid * 256;
            for (int s = 0; s < 256; s += 4) {
                f32x4 hv = *(const f32x4*)(fb + s);
                f32x4 w4 = *(const f32x4*)(wp + s);
                acc += hv[0] * w4[0] + hv[1] * w4[1] + hv[2] * w4[2] + hv[3] * w4[3];
            }
            out[((long)(b0c + nsl) * 513 + Tt) * OUTd + tid] = acc;
        }
    }
}

extern "C" void kernel_launch(void* const* d_in, const int* in_sizes, int n_in,
                              void* d_out, int out_size, void* d_ws, size_t ws_size,
                              hipStream_t stream) {
    const float* x0      = (const float*)d_in[0];
    const float* logsigs = (const float*)d_in[1];
    const float* iW1 = (const float*)d_in[2];
    const float* ib1 = (const float*)d_in[3];
    const float* iW2 = (const float*)d_in[4];
    const float* ib2 = (const float*)d_in[5];
    const float* iW3 = (const float*)d_in[6];
    const float* ib3 = (const float*)d_in[7];
    const float* vW1 = (const float*)d_in[8];
    const float* vb1 = (const float*)d_in[9];
    const float* vW2 = (const float*)d_in[10];
    const float* vb2 = (const float*)d_in[11];
    const float* vW3 = (const float*)d_in[12];
    const float* vb3 = (const float*)d_in[13];
    const float* roW = (const float*)d_in[14];
    const float* rob = (const float*)d_in[15];
    float* out = (float*)d_out;

    char* p = (char*)d_ws;
    float* hA            = (float*)p;                         // 262144 B
    float* hB            = (float*)(p + 262144);              // 262144 B
    unsigned short* w1h  = (unsigned short*)(p + 524288);     // 131072 B
    unsigned short* w1l  = (unsigned short*)(p + 655360);     // 131072 B
    unsigned short* w2h  = (unsigned short*)(p + 786432);     // 131072 B
    unsigned short* w2l  = (unsigned short*)(p + 917504);     // 131072 B
    unsigned short* w3h  = (unsigned short*)(p + 1048576);    // 4718592 B
    unsigned short* w3l  = (unsigned short*)(p + 5767168);    // 4718592 B
    int* slots           = (int*)(p + 10485760);              // barrier tree (>=1280 B)

    hipMemsetAsync(slots, 0, 4096, stream);
    rde_fused<<<dim3(256), dim3(256), 0, stream>>>(
        x0, logsigs, iW1, ib1, iW2, ib2, iW3, ib3,
        vW1, vb1, vW2, vb2, vW3, vb3, roW, rob, out,
        hA, hB, w1h, w1l, w2h, w2l, w3h, w3l, slots);
}

// Round 2
// 28038.733 us; speedup vs baseline: 1.1803x; 1.1803x over previous
//
#include <hip/hip_runtime.h>

// Problem constants (B,T,S,L,D_IN,OUT,W = 256,512,256,36,8,10,256)
#define Tt   512
#define Ll   36
#define DIN  8
#define OUTd 10

typedef __attribute__((ext_vector_type(8))) short short8;
typedef __attribute__((ext_vector_type(4))) float f32x4;

__device__ __forceinline__ unsigned short f2bf(float f) {
    union { float f; unsigned int u; } v; v.f = f;
    unsigned int r = v.u + 0x7fffu + ((v.u >> 16) & 1u);   // RNE
    return (unsigned short)(r >> 16);
}
__device__ __forceinline__ float bf2f(unsigned short u) {
    union { unsigned int u; float f; } v; v.u = ((unsigned int)u) << 16;
    return v.f;
}
__device__ __forceinline__ float sp_f(float x) {      // jax.nn.softplus
    return fmaxf(x, 0.f) + __logf(1.f + __expf(-fabsf(x)));
}
__device__ __forceinline__ float tanh_f(float x) {
    float e = __expf(2.f * x);
    return 1.f - 2.f / (e + 1.f);
}

// ---- agent-scope (sc1 / LLC-coherent) helpers: cross-XCD-safe ----
__device__ __forceinline__ unsigned long long ldg64(const void* p) {
    return __hip_atomic_load((const unsigned long long*)p, __ATOMIC_RELAXED, __HIP_MEMORY_SCOPE_AGENT);
}
__device__ __forceinline__ void stg64(void* p, unsigned long long v) {
    __hip_atomic_store((unsigned long long*)p, v, __ATOMIC_RELAXED, __HIP_MEMORY_SCOPE_AGENT);
}
__device__ __forceinline__ void sth(unsigned short* p, unsigned short v) {
    __hip_atomic_store(p, v, __ATOMIC_RELAXED, __HIP_MEMORY_SCOPE_AGENT);
}
union U64F2 { unsigned long long u; float f[2]; unsigned short s[4]; };
union S8U   { unsigned long long u[2]; short8 v; };

// ---- LDS layout ----
struct GScr { short hh[64*264], hl[64*264], z1h[64*264], z1l[64*264]; };           // 135168 B
struct CScr { short w3s[2][18432]; float lss[64*Ll]; float ml[64*148]; float b3s[144]; }; // 121408 B
struct IScr { float x0s[32][DIN]; float h1[32*257]; float h2[32*257]; };            // 66816 B
union  Scr  { GScr g; CScr c; IScr in; };

// ---- tree grid barrier: 8 group counters -> super counter -> 8 per-group release words ----
__device__ __forceinline__ void gbar(int* bar, int gen) {
    __syncthreads();
    if (threadIdx.x == 0) {
        const int g = blockIdx.x & 7;
        int old = __hip_atomic_fetch_add(bar + g * 32, 1, __ATOMIC_RELAXED, __HIP_MEMORY_SCOPE_AGENT);
        if (old == gen * 32 - 1) {                       // last block of this group
            int o2 = __hip_atomic_fetch_add(bar + 8 * 32, 1, __ATOMIC_RELAXED, __HIP_MEMORY_SCOPE_AGENT);
            if (o2 == gen * 8 - 1) {                     // last group overall -> release all groups
#pragma unroll
                for (int gg = 0; gg < 8; ++gg)
                    __hip_atomic_store(bar + (9 + gg) * 32, gen, __ATOMIC_RELAXED, __HIP_MEMORY_SCOPE_AGENT);
            }
        }
        while (__hip_atomic_load(bar + (9 + g) * 32, __ATOMIC_RELAXED, __HIP_MEMORY_SCOPE_AGENT) < gen)
            __builtin_amdgcn_s_sleep(2);
    }
    __syncthreads();
}

// cast 4 consecutive f32 -> hi/lo bf16 (row-major, used for W3)
__device__ __forceinline__ void cast_quad(const float* src, unsigned short* dh,
                                          unsigned short* dl, long u) {
    f32x4 f = *(const f32x4*)(src + u * 4);
    U64F2 H, L;
#pragma unroll
    for (int q = 0; q < 4; ++q) {
        float v = f[q];
        unsigned short hi = f2bf(v);
        H.s[q] = hi;
        L.s[q] = f2bf(v - bf2f(hi));
    }
    stg64(dh + u * 4, H.u);
    stg64(dl + u * 4, L.u);
}

// cast 8 consecutive k of W[n][k] (256x256) into frag-contiguous transposed layout:
// t[(k>>5)*256 + n][ (k>>3)&3 ][ k&7 ]  => offset ((k>>5)*256+n)*32 + ((k>>3)&3)*8 + (k&7)
// A wave's 64 lanes reading frag (n=base+l15, quad) then cover a contiguous 1KB window.
__device__ __forceinline__ void cast_w8(const float* src, unsigned short* dh,
                                        unsigned short* dl, int u) {
    int n = u >> 5, k8 = u & 31;
    const float* sp = src + n * 256 + k8 * 8;
    f32x4 f0 = *(const f32x4*)sp;
    f32x4 f1 = *(const f32x4*)(sp + 4);
    U64F2 H0, H1, L0, L1;
#pragma unroll
    for (int q = 0; q < 4; ++q) {
        unsigned short a = f2bf(f0[q]); H0.s[q] = a; L0.s[q] = f2bf(f0[q] - bf2f(a));
        unsigned short b = f2bf(f1[q]); H1.s[q] = b; L1.s[q] = f2bf(f1[q] - bf2f(b));
    }
    long d = ((long)(k8 >> 2) * 256 + n) * 32 + (k8 & 3) * 8;
    stg64(dh + d, H0.u);  stg64(dh + d + 4, H1.u);
    stg64(dl + d, L0.u);  stg64(dl + d + 4, L1.u);
}

// one MLP stage: Z = softplus(A @ B^T + bias). A/Z in LDS [64][264] hi/lo bf16.
// B in global frag-contiguous transposed layout (see cast_w8): coalesced 16B/lane loads.
#define MLP_STAGE(Ah, Al, Bh, Bl, BIAS, Zh, Zl) do {                                        \
    f32x4 acc_[4][4];                                                                        \
    _Pragma("unroll")                                                                        \
    for (int rb_ = 0; rb_ < 4; ++rb_) {                                                      \
      _Pragma("unroll")                                                                      \
      for (int j_ = 0; j_ < 4; ++j_) acc_[rb_][j_] = zero4;                                  \
    }                                                                                        \
    for (int k0_ = 0; k0_ < 256; k0_ += 32) {                                                \
      short8 bh_[4], bl_[4];                                                                 \
      _Pragma("unroll")                                                                      \
      for (int j_ = 0; j_ < 4; ++j_) {                                                       \
        int n_ = (4 * wv + j_) * 16 + l15;                                                   \
        long bo_ = ((long)(k0_ >> 5) * 256 + n_) * 32 + quad * 8;                            \
        bh_[j_] = *(const short8*)(const void*)((Bh) + bo_);                                 \
        bl_[j_] = *(const short8*)(const void*)((Bl) + bo_);                                 \
      }                                                                                      \
      _Pragma("unroll")                                                                      \
      for (int rb_ = 0; rb_ < 4; ++rb_) {                                                    \
        short8 ah_ = *(const short8*)(const void*)&(Ah)[(rb_ * 16 + l15) * 264 + k0_ + quad * 8]; \
        short8 al_ = *(const short8*)(const void*)&(Al)[(rb_ * 16 + l15) * 264 + k0_ + quad * 8]; \
        _Pragma("unroll")                                                                    \
        for (int j_ = 0; j_ < 4; ++j_) {                                                     \
          acc_[rb_][j_] = __builtin_amdgcn_mfma_f32_16x16x32_bf16(ah_, bh_[j_], acc_[rb_][j_], 0, 0, 0); \
          acc_[rb_][j_] = __builtin_amdgcn_mfma_f32_16x16x32_bf16(ah_, bl_[j_], acc_[rb_][j_], 0, 0, 0); \
          acc_[rb_][j_] = __builtin_amdgcn_mfma_f32_16x16x32_bf16(al_, bh_[j_], acc_[rb_][j_], 0, 0, 0); \
        }                                                                                    \
      }                                                                                      \
    }                                                                                        \
    _Pragma("unroll")                                                                        \
    for (int rb_ = 0; rb_ < 4; ++rb_) {                                                      \
      _Pragma("unroll")                                                                      \
      for (int j_ = 0; j_ < 4; ++j_) {                                                       \
        int n_ = (4 * wv + j_) * 16 + l15;                                                   \
        float bs_ = (BIAS)[n_];                                                              \
        _Pragma("unroll")                                                                    \
        for (int r_ = 0; r_ < 4; ++r_) {                                                     \
          int row_ = rb_ * 16 + quad * 4 + r_;                                               \
          float v_ = sp_f(acc_[rb_][j_][r_] + bs_);                                          \
          unsigned short hi_ = f2bf(v_);                                                     \
          (Zh)[row_ * 264 + n_] = (short)hi_;                                                \
          (Zl)[row_ * 264 + n_] = (short)f2bf(v_ - bf2f(hi_));                               \
        }                                                                                    \
      }                                                                                      \
    }                                                                                        \
  } while (0)

__global__ __launch_bounds__(256, 1) void rde_fused2(
    const float* __restrict__ x0, const float* __restrict__ logsigs,
    const float* __restrict__ iW1, const float* __restrict__ ib1,
    const float* __restrict__ iW2, const float* __restrict__ ib2,
    const float* __restrict__ iW3, const float* __restrict__ ib3,
    const float* __restrict__ vW1, const float* __restrict__ vb1,
    const float* __restrict__ vW2, const float* __restrict__ vb2,
    const float* __restrict__ vW3, const float* __restrict__ vb3,
    const float* __restrict__ roW, const float* __restrict__ rob,
    float* __restrict__ out,
    unsigned short* hhA, unsigned short* hlA,
    unsigned short* hhB, unsigned short* hlB,
    unsigned short* w1th, unsigned short* w1tl,
    unsigned short* w2th, unsigned short* w2tl,
    unsigned short* w3h, unsigned short* w3l, int* slots) {
    __shared__ Scr S;
    __shared__ float hloc[256];   // persistent h slice (64 rows x 4 s), exact f32 accumulator
    __shared__ float rtmp[44];    // readout partials (4 waves x 10 outputs)
    const int tid = threadIdx.x, blk = blockIdx.x;
    const int lane = tid & 63, wv = tid >> 6, quad = lane >> 4, l15 = lane & 15;
    // XCD-aware slot mapping: same-XCD blocks share only 8 W3 slices -> L2-resident. Bijective.
    const int nsl = (blk & 7) * 8 + ((blk >> 3) & 7);
    const int bch = blk >> 6;
    const int b0c = bch * 64, n0 = nsl * 144, s0 = nsl * 4;
    const f32x4 zero4 = {0.f, 0.f, 0.f, 0.f};
    int gen = 0;

    // ===== phase 0: init MLP (blk<8), W1/W2 transposed cast (8..15), W3 cast (16..255) =====
    if (blk < 8) {
        IScr& I = S.in;
        const int b0 = blk * 32;
        I.x0s[tid >> 3][tid & 7] = x0[(b0 + (tid >> 3)) * DIN + (tid & 7)];
        __syncthreads();
        const int j = tid;
        {
            float w[DIN];
#pragma unroll
            for (int k = 0; k < DIN; ++k) w[k] = iW1[j * DIN + k];
            float bias = ib1[j];
            for (int r = 0; r < 32; ++r) {
                float acc = bias;
#pragma unroll
                for (int k = 0; k < DIN; ++k) acc += I.x0s[r][k] * w[k];
                I.h1[r * 257 + j] = sp_f(acc);
            }
        }
        __syncthreads();
        {
            float bias = ib2[j];
            for (int rb = 0; rb < 4; ++rb) {
                float a8[8];
#pragma unroll
                for (int rr = 0; rr < 8; ++rr) a8[rr] = bias;
                for (int k = 0; k < 256; ++k) {
                    float wvv = iW2[j * 256 + k];
#pragma unroll
                    for (int rr = 0; rr < 8; ++rr) a8[rr] += I.h1[(rb * 8 + rr) * 257 + k] * wvv;
                }
#pragma unroll
                for (int rr = 0; rr < 8; ++rr) I.h2[(rb * 8 + rr) * 257 + j] = sp_f(a8[rr]);
            }
        }
        __syncthreads();
        {
            float bias = ib3[j];
            for (int rb = 0; rb < 4; ++rb) {
                float a8[8];
#pragma unroll
                for (int rr = 0; rr < 8; ++rr) a8[rr] = bias;
                for (int k = 0; k < 256; ++k) {
                    float wvv = iW3[j * 256 + k];
#pragma unroll
                    for (int rr = 0; rr < 8; ++rr) a8[rr] += I.h2[(rb * 8 + rr) * 257 + k] * wvv;
                }
#pragma unroll
                for (int rr = 0; rr < 8; ++rr) {   // publish h0 pre-split to LLC
                    float v = a8[rr];
                    unsigned short hi = f2bf(v);
                    sth(&hhA[(b0 + rb * 8 + rr) * 256 + j], hi);
                    sth(&hlA[(b0 + rb * 8 + rr) * 256 + j], f2bf(v - bf2f(hi)));
                }
            }
        }
    } else if (blk < 16) {
        const int idx = blk - 8;
        const float* src = (idx < 4) ? vW1 : vW2;
        unsigned short* dh = (idx < 4) ? w1th : w2th;
        unsigned short* dl = (idx < 4) ? w1tl : w2tl;
        const int part = idx & 3;
        for (int u = part * 2048 + tid; u < (part + 1) * 2048; u += 256)
            cast_w8(src, dh, dl, u);
    } else {
        for (long u = (long)(blk - 16) * 256 + tid; u < 589824; u += 240L * 256)
            cast_quad(vW3, w3h, w3l, u);
    }
    gbar(slots, ++gen);

    // load persistent h slice (h0) once (hi+lo reconstruct, ~1e-5 rel)
    if (tid < 64) {
        U64F2 a, b;
        a.u = ldg64(hhA + (b0c + tid) * 256 + s0);
        b.u = ldg64(hlA + (b0c + tid) * 256 + s0);
#pragma unroll
        for (int q = 0; q < 4; ++q) hloc[tid * 4 + q] = bf2f(a.s[q]) + bf2f(b.s[q]);
    }

    // ================= main scan: ONE grid barrier per step =================
    for (int t = 0; t < Tt; ++t) {
        GScr& G = S.g;
        const unsigned short* hhs = (t & 1) ? hhB : hhA;
        const unsigned short* hls = (t & 1) ? hlB : hlA;
        unsigned short* hhd = (t & 1) ? hhA : hhB;
        unsigned short* hld = (t & 1) ? hlA : hlB;

        // ---- gather pre-split h(t) [64 x 256] hi/lo into LDS (pure copy, coalesced) ----
        for (int u = tid; u < 4096; u += 256) {
            int r = u >> 6, c = (u & 63) * 4;
            *(unsigned long long*)(void*)&G.hh[r * 264 + c] = ldg64(hhs + (b0c + r) * 256 + c);
            *(unsigned long long*)(void*)&G.hl[r * 264 + c] = ldg64(hls + (b0c + r) * 256 + c);
        }
        __syncthreads();

        // ---- readout partials for out[b0c+nsl, t, :] ----
        if (lane < OUTd) {
            const int o = lane;
            float acc = 0.f;
            const short* ph = &G.hh[nsl * 264 + wv * 64];
            const short* pl = &G.hl[nsl * 264 + wv * 64];
            const float* wp = roW + o * 256 + wv * 64;
            for (int s = 0; s < 64; s += 8) {
                short8 vh = *(const short8*)(const void*)(ph + s);
                short8 vl = *(const short8*)(const void*)(pl + s);
                f32x4 w0 = *(const f32x4*)(wp + s);
                f32x4 w1 = *(const f32x4*)(wp + s + 4);
#pragma unroll
                for (int q = 0; q < 4; ++q) {
                    acc += (bf2f((unsigned short)vh[q]) + bf2f((unsigned short)vl[q])) * w0[q];
                    acc += (bf2f((unsigned short)vh[q + 4]) + bf2f((unsigned short)vl[q + 4])) * w1[q];
                }
            }
            rtmp[wv * 10 + o] = acc;
        }

        // ---- stage 1: z1 = sp(h W1^T) ----
        MLP_STAGE(G.hh, G.hl, w1th, w1tl, vb1, G.z1h, G.z1l);
        __syncthreads();

        // readout: combine wave partials, write out[:, t, :]
        if (tid < OUTd)
            out[((long)(b0c + nsl) * 513 + t) * OUTd + tid] =
                rob[tid] + rtmp[tid] + rtmp[10 + tid] + rtmp[20 + tid] + rtmp[30 + tid];

        // ---- stage 2: z2 = sp(z1 W2^T) -> back into hh/hl ----
        MLP_STAGE(G.z1h, G.z1l, w2th, w2tl, vb2, G.hh, G.hl);
        __syncthreads();

        // ---- load z2 A-fragments into registers (before W3 staging overwrites LDS) ----
        S8U zh[8], zl[8];
        {
            const int rl = 16 * wv + l15;
#pragma unroll
            for (int kk = 0; kk < 8; ++kk) {
                zh[kk].v = *(const short8*)(const void*)&G.hh[rl * 264 + kk * 32 + quad * 8];
                zl[kk].v = *(const short8*)(const void*)&G.hl[rl * 264 + kk * 32 + quad * 8];
            }
        }
        __syncthreads();

        // ---- W3 phase: m = tanh(z2 W3^T + b3); h += einsum(m, ls) ----
        {
            CScr& C = S.c;
            for (int i = tid; i < 64 * Ll; i += 256) {
                int r = i / Ll, l = i - r * Ll;
                C.lss[i] = logsigs[((long)(b0c + r) * Tt + t) * Ll + l];
            }
            if (tid < 144) C.b3s[tid] = vb3[n0 + tid];
            // stage W3 chunk 0 (k 0..63), frag-contiguous layout
            for (int u = tid; u < 2304; u += 256) {
                int isLo = (u >= 1152) ? 1 : 0;
                int uu = u - isLo * 1152;
                int r = uu >> 3, p = uu & 7;
                const unsigned short* src = isLo ? w3l : w3h;
                short8 v = *(const short8*)(const void*)(src + (long)(n0 + r) * 256 + p * 8);
                int d = ((p >> 2) * 9 + (r >> 4)) * 64 + (p & 3) * 16 + (r & 15);
                *(short8*)(void*)(C.w3s[0] + isLo * 9216 + d * 8) = v;
            }
            __syncthreads();
            f32x4 acc[9];
#pragma unroll
            for (int nt = 0; nt < 9; ++nt) acc[nt] = zero4;
#pragma unroll
            for (int c4 = 0; c4 < 4; ++c4) {
                if (c4 < 3) {   // prefetch next W3 chunk into other buffer
                    for (int u = tid; u < 2304; u += 256) {
                        int isLo = (u >= 1152) ? 1 : 0;
                        int uu = u - isLo * 1152;
                        int r = uu >> 3, p = uu & 7;
                        const unsigned short* src = isLo ? w3l : w3h;
                        short8 v = *(const short8*)(const void*)(src + (long)(n0 + r) * 256 + (c4 + 1) * 64 + p * 8);
                        int d = ((p >> 2) * 9 + (r >> 4)) * 64 + (p & 3) * 16 + (r & 15);
                        *(short8*)(void*)(C.w3s[(c4 + 1) & 1] + isLo * 9216 + d * 8) = v;
                    }
                }
                const short* wb = C.w3s[c4 & 1];
#pragma unroll
                for (int sub = 0; sub < 2; ++sub) {
                    const int kk = c4 * 2 + sub;
#pragma unroll
                    for (int nt = 0; nt < 9; ++nt) {
                        const short* pp = wb + ((sub * 9 + nt) * 64 + lane) * 8;
                        short8 bh = *(const short8*)(const void*)pp;
                        short8 bl = *(const short8*)(const void*)(pp + 9216);
                        acc[nt] = __builtin_amdgcn_mfma_f32_16x16x32_bf16(zh[kk].v, bh, acc[nt], 0, 0, 0);
                        acc[nt] = __builtin_amdgcn_mfma_f32_16x16x32_bf16(zh[kk].v, bl, acc[nt], 0, 0, 0);
                        acc[nt] = __builtin_amdgcn_mfma_f32_16x16x32_bf16(zl[kk].v, bh, acc[nt], 0, 0, 0);
                    }
                }
                __syncthreads();
            }
            // epilogue: tanh -> ml
#pragma unroll
            for (int nt = 0; nt < 9; ++nt) {
                int nl = nt * 16 + l15;
                float bias = C.b3s[nl];
#pragma unroll
                for (int r = 0; r < 4; ++r) {
                    int row = 16 * wv + quad * 4 + r;
                    C.ml[row * 148 + nl] = tanh_f(acc[nt][r] + bias);
                }
            }
            __syncthreads();
            // l-contraction: each thread owns one (row, sr): hloc[tid] += dot36
            {
                int row = tid >> 2, sr = tid & 3;
                const f32x4* mp = (const f32x4*)(const void*)&C.ml[row * 148 + sr * 36];
                const f32x4* lp = (const f32x4*)(const void*)&C.lss[row * 36];
                float a = 0.f;
#pragma unroll
                for (int q = 0; q < 9; ++q) {
                    f32x4 m4 = mp[q], l4 = lp[q];
                    a += m4[0] * l4[0] + m4[1] * l4[1] + m4[2] * l4[2] + m4[3] * l4[3];
                }
                hloc[tid] += a;
            }
            __syncthreads();
            if (tid < 64) {   // publish h slice pre-split (exclusive owner) to the OTHER buffer
                U64F2 H, L;
#pragma unroll
                for (int q = 0; q < 4; ++q) {
                    float v = hloc[tid * 4 + q];
                    unsigned short hi = f2bf(v);
                    H.s[q] = hi;
                    L.s[q] = f2bf(v - bf2f(hi));
                }
                stg64(hhd + (b0c + tid) * 256 + s0, H.u);
                stg64(hld + (b0c + tid) * 256 + s0, L.u);
            }
        }
        gbar(slots, ++gen);
    }

    // ---- final readout out[:, 512, :] (h(512) lives in the A buffers since Tt is even) ----
    {
        float* fb = S.c.lss;   // reuse as f32 row buffer
        if (tid < 64) {
            U64F2 a, b;
            a.u = ldg64(hhA + (long)(b0c + nsl) * 256 + tid * 4);
            b.u = ldg64(hlA + (long)(b0c + nsl) * 256 + tid * 4);
#pragma unroll
            for (int q = 0; q < 4; ++q) fb[tid * 4 + q] = bf2f(a.s[q]) + bf2f(b.s[q]);
        }
        __syncthreads();
        if (tid < OUTd) {
            float acc = rob[tid];
            const float* wp = roW + tid * 256;
            for (int s = 0; s < 256; s += 4) {
                f32x4 hv = *(const f32x4*)(fb + s);
                f32x4 w4 = *(const f32x4*)(wp + s);
                acc += hv[0] * w4[0] + hv[1] * w4[1] + hv[2] * w4[2] + hv[3] * w4[3];
            }
            out[((long)(b0c + nsl) * 513 + Tt) * OUTd + tid] = acc;
        }
    }
}

extern "C" void kernel_launch(void* const* d_in, const int* in_sizes, int n_in,
                              void* d_out, int out_size, void* d_ws, size_t ws_size,
                              hipStream_t stream) {
    const float* x0      = (const float*)d_in[0];
    const float* logsigs = (const float*)d_in[1];
    const float* iW1 = (const float*)d_in[2];
    const float* ib1 = (const float*)d_in[3];
    const float* iW2 = (const float*)d_in[4];
    const float* ib2 = (const float*)d_in[5];
    const float* iW3 = (const float*)d_in[6];
    const float* ib3 = (const float*)d_in[7];
    const float* vW1 = (const float*)d_in[8];
    const float* vb1 = (const float*)d_in[9];
    const float* vW2 = (const float*)d_in[10];
    const float* vb2 = (const float*)d_in[11];
    const float* vW3 = (const float*)d_in[12];
    const float* vb3 = (const float*)d_in[13];
    const float* roW = (const float*)d_in[14];
    const float* rob = (const float*)d_in[15];
    float* out = (float*)d_out;

    char* p = (char*)d_ws;
    unsigned short* hhA  = (unsigned short*)p;                // 131072 B
    unsigned short* hlA  = (unsigned short*)(p + 131072);     // 131072 B
    unsigned short* hhB  = (unsigned short*)(p + 262144);     // 131072 B
    unsigned short* hlB  = (unsigned short*)(p + 393216);     // 131072 B
    unsigned short* w1th = (unsigned short*)(p + 524288);     // 131072 B
    unsigned short* w1tl = (unsigned short*)(p + 655360);     // 131072 B
    unsigned short* w2th = (unsigned short*)(p + 786432);     // 131072 B
    unsigned short* w2tl = (unsigned short*)(p + 917504);     // 131072 B
    unsigned short* w3h  = (unsigned short*)(p + 1048576);    // 4718592 B
    unsigned short* w3l  = (unsigned short*)(p + 5767168);    // 4718592 B
    int* slots           = (int*)(p + 10485760);              // barrier tree (>=2052 B)

    hipMemsetAsync(slots, 0, 4096, stream);
    rde_fused2<<<dim3(256), dim3(256), 0, stream>>>(
        x0, logsigs, iW1, ib1, iW2, ib2, iW3, ib3,
        vW1, vb1, vW2, vb2, vW3, vb3, roW, rob, out,
        hhA, hlA, hhB, hlB, w1th, w1tl, w2th, w2tl, w3h, w3l, slots);
}

// Round 4
// 15433.693 us; speedup vs baseline: 2.1443x; 1.8167x over previous
//
#include <hip/hip_runtime.h>

// Problem constants (B,T,S,L,D_IN,OUT,W = 256,512,256,36,8,10,256)
#define Tt   512
#define Ll   36
#define DIN  8
#define OUTd 10

typedef __attribute__((ext_vector_type(8))) short short8;
typedef __attribute__((ext_vector_type(4))) float f32x4;

__device__ __forceinline__ unsigned short f2bf(float f) {
    union { float f; unsigned int u; } v; v.f = f;
    unsigned int r = v.u + 0x7fffu + ((v.u >> 16) & 1u);   // RNE
    return (unsigned short)(r >> 16);
}
__device__ __forceinline__ float bf2f(unsigned short u) {
    union { unsigned int u; float f; } v; v.u = ((unsigned int)u) << 16;
    return v.f;
}
__device__ __forceinline__ float sp_f(float x) {      // jax.nn.softplus
    return fmaxf(x, 0.f) + __logf(1.f + __expf(-fabsf(x)));
}
__device__ __forceinline__ float tanh_f(float x) {
    float e = __expf(2.f * x);
    return 1.f - 2.f / (e + 1.f);
}

// ---- agent-scope (sc1 / LLC-coherent) helpers: cross-XCD-safe ----
__device__ __forceinline__ unsigned long long ldg64(const void* p) {
    return __hip_atomic_load((const unsigned long long*)p, __ATOMIC_RELAXED, __HIP_MEMORY_SCOPE_AGENT);
}
__device__ __forceinline__ void stg64(void* p, unsigned long long v) {
    __hip_atomic_store((unsigned long long*)p, v, __ATOMIC_RELAXED, __HIP_MEMORY_SCOPE_AGENT);
}
__device__ __forceinline__ void sth(unsigned short* p, unsigned short v) {
    __hip_atomic_store(p, v, __ATOMIC_RELAXED, __HIP_MEMORY_SCOPE_AGENT);
}
union U64F2 { unsigned long long u; float f[2]; unsigned short s[4]; };

// ---- LDS layout ----
struct GScr {
    short hh[16*264], hl[16*264];      // gathered h(t), hi/lo bf16
    short z1h[16*264], z1l[16*264];    // stage-1 activations
    short z2h[16*264], z2l[16*264];    // stage-2 activations
    float lss[16*36];                  // logsigs slice
    float ml[16*584];                  // tanh(m) slice [16 rows x 576 n]
};                                      // ~90.4 KB
struct IScr { float x0s[32][DIN]; float h1[32*257]; float h2[32*257]; };
union  Scr  { GScr g; IScr in; };

// ---- full-grid tree barrier (phase 0 only); touches slots[0 .. 512] inclusive ----
__device__ __forceinline__ void gbar(int* bar, int gen) {
    __syncthreads();
    if (threadIdx.x == 0) {
        const int g = blockIdx.x & 7;
        int old = __hip_atomic_fetch_add(bar + g * 32, 1, __ATOMIC_RELAXED, __HIP_MEMORY_SCOPE_AGENT);
        if (old == gen * 32 - 1) {
            int o2 = __hip_atomic_fetch_add(bar + 8 * 32, 1, __ATOMIC_RELAXED, __HIP_MEMORY_SCOPE_AGENT);
            if (o2 == gen * 8 - 1) {
#pragma unroll
                for (int gg = 0; gg < 8; ++gg)
                    __hip_atomic_store(bar + (9 + gg) * 32, gen, __ATOMIC_RELAXED, __HIP_MEMORY_SCOPE_AGENT);
            }
        }
        while (__hip_atomic_load(bar + (9 + g) * 32, __ATOMIC_RELAXED, __HIP_MEMORY_SCOPE_AGENT) < gen)
            __builtin_amdgcn_s_sleep(2);
    }
    __syncthreads();
}

// ---- chunk-local barrier: 16 blocks on one monotone counter ----
__device__ __forceinline__ void cbar(int* c, int gen) {
    __syncthreads();   // drains each wave's sc1 stores (vmcnt 0) before arrive
    if (threadIdx.x == 0) {
        __hip_atomic_fetch_add(c, 1, __ATOMIC_RELAXED, __HIP_MEMORY_SCOPE_AGENT);
        while (__hip_atomic_load(c, __ATOMIC_RELAXED, __HIP_MEMORY_SCOPE_AGENT) < gen * 16)
            __builtin_amdgcn_s_sleep(1);
    }
    __syncthreads();
}

// cast 8 consecutive k of W[n][k] (N x 256) into frag-contiguous transposed layout:
// element (n,k) -> ((k>>5)*N + n)*32 + ((k>>3)&3)*8 + (k&7)
// => a wave's B-frag load (n = base+l15, +quad*8) is a contiguous coalesced window.
__device__ __forceinline__ void cast_w8n(const float* src, unsigned short* dh,
                                         unsigned short* dl, long u, int N) {
    long n = u >> 5; int k8 = (int)(u & 31);
    const float* sp = src + n * 256 + k8 * 8;
    f32x4 f0 = *(const f32x4*)sp;
    f32x4 f1 = *(const f32x4*)(sp + 4);
    U64F2 H0, H1, L0, L1;
#pragma unroll
    for (int q = 0; q < 4; ++q) {
        unsigned short a = f2bf(f0[q]); H0.s[q] = a; L0.s[q] = f2bf(f0[q] - bf2f(a));
        unsigned short b = f2bf(f1[q]); H1.s[q] = b; L1.s[q] = f2bf(f1[q] - bf2f(b));
    }
    long d = ((long)(k8 >> 2) * N + n) * 32 + (k8 & 3) * 8;
    stg64(dh + d, H0.u);  stg64(dh + d + 4, H1.u);
    stg64(dl + d, L0.u);  stg64(dl + d + 4, L1.u);
}

// one MLP stage for 16 rows: Z = softplus(A @ B^T + bias); A/Z in LDS [16][264] hi/lo,
// B in global frag-contiguous transposed layout (cast_w8n, N=256).
#define MLP_STAGE16(Ah, Al, Bh, Bl, BIAS, Zh, Zl) do {                                      \
    f32x4 acc_[4] = {zero4, zero4, zero4, zero4};                                            \
    for (int k0_ = 0; k0_ < 256; k0_ += 32) {                                                \
      short8 ah_ = *(const short8*)(const void*)&(Ah)[l15 * 264 + k0_ + quad * 8];           \
      short8 al_ = *(const short8*)(const void*)&(Al)[l15 * 264 + k0_ + quad * 8];           \
      _Pragma("unroll")                                                                      \
      for (int j_ = 0; j_ < 4; ++j_) {                                                       \
        int n_ = (4 * wv + j_) * 16 + l15;                                                   \
        long bo_ = ((long)(k0_ >> 5) * 256 + n_) * 32 + quad * 8;                            \
        short8 bh_ = *(const short8*)(const void*)((Bh) + bo_);                              \
        short8 bl_ = *(const short8*)(const void*)((Bl) + bo_);                              \
        acc_[j_] = __builtin_amdgcn_mfma_f32_16x16x32_bf16(ah_, bh_, acc_[j_], 0, 0, 0);     \
        acc_[j_] = __builtin_amdgcn_mfma_f32_16x16x32_bf16(ah_, bl_, acc_[j_], 0, 0, 0);     \
        acc_[j_] = __builtin_amdgcn_mfma_f32_16x16x32_bf16(al_, bh_, acc_[j_], 0, 0, 0);     \
      }                                                                                      \
    }                                                                                        \
    _Pragma("unroll")                                                                        \
    for (int j_ = 0; j_ < 4; ++j_) {                                                         \
      int n_ = (4 * wv + j_) * 16 + l15;                                                     \
      float bs_ = (BIAS)[n_];                                                                \
      _Pragma("unroll")                                                                      \
      for (int r_ = 0; r_ < 4; ++r_) {                                                       \
        int row_ = quad * 4 + r_;                                                            \
        float v_ = sp_f(acc_[j_][r_] + bs_);                                                 \
        unsigned short hi_ = f2bf(v_);                                                       \
        (Zh)[row_ * 264 + n_] = (short)hi_;                                                  \
        (Zl)[row_ * 264 + n_] = (short)f2bf(v_ - bf2f(hi_));                                 \
      }                                                                                      \
    }                                                                                        \
  } while (0)

__global__ __launch_bounds__(256, 1) void rde_fused4(
    const float* __restrict__ x0, const float* __restrict__ logsigs,
    const float* __restrict__ iW1, const float* __restrict__ ib1,
    const float* __restrict__ iW2, const float* __restrict__ ib2,
    const float* __restrict__ iW3, const float* __restrict__ ib3,
    const float* __restrict__ vW1, const float* __restrict__ vb1,
    const float* __restrict__ vW2, const float* __restrict__ vb2,
    const float* __restrict__ vW3, const float* __restrict__ vb3,
    const float* __restrict__ roW, const float* __restrict__ rob,
    float* __restrict__ out,
    unsigned short* hhA, unsigned short* hlA,
    unsigned short* hhB, unsigned short* hlB,
    unsigned short* w1th, unsigned short* w1tl,
    unsigned short* w2th, unsigned short* w2tl,
    unsigned short* w3th, unsigned short* w3tl, int* slots) {
    __shared__ Scr S;
    __shared__ float hloc[256];   // owned h sub-tile [16 rows x 16 s], exact f32
    __shared__ float rtmp[44];    // readout partials (4 waves x 10)
    const int tid = threadIdx.x, blk = blockIdx.x;
    const int lane = tid & 63, wv = tid >> 6, quad = lane >> 4, l15 = lane & 15;
    // blk bits: b0-2 = xcd-ish, b3-6 = chunk, b7 = slot parity.
    // slot = ((blk&7)<<1)|(blk>>7): each XCD's 32 blocks share only 2 W3 slices (1.2 MB).
    const int chunk = (blk >> 3) & 15;
    const int sl = ((blk & 7) << 1) | (blk >> 7);
    const int b0c16 = chunk * 16;        // 16 batch rows owned by this chunk
    const int s0g = sl * 16;             // owned s-slice
    const int n0g = sl * 576;            // owned W3 n-slice
    // chunk counters at slots+1024: DISJOINT from gbar's range [0, 512]
    // (bugfix R4: slots+512 aliased gbar's group-7 release word -> early release race)
    int* cb = slots + 1024 + chunk * 32;
    const f32x4 zero4 = {0.f, 0.f, 0.f, 0.f};

    // ===== phase 0: init MLP (blk<8), W1/W2 cast (8..15), W3 transposed cast (16..255) =====
    if (blk < 8) {
        IScr& I = S.in;
        const int b0 = blk * 32;
        I.x0s[tid >> 3][tid & 7] = x0[(b0 + (tid >> 3)) * DIN + (tid & 7)];
        __syncthreads();
        const int j = tid;
        {
            float w[DIN];
#pragma unroll
            for (int k = 0; k < DIN; ++k) w[k] = iW1[j * DIN + k];
            float bias = ib1[j];
            for (int r = 0; r < 32; ++r) {
                float acc = bias;
#pragma unroll
                for (int k = 0; k < DIN; ++k) acc += I.x0s[r][k] * w[k];
                I.h1[r * 257 + j] = sp_f(acc);
            }
        }
        __syncthreads();
        {
            float bias = ib2[j];
            for (int rb = 0; rb < 4; ++rb) {
                float a8[8];
#pragma unroll
                for (int rr = 0; rr < 8; ++rr) a8[rr] = bias;
                for (int k = 0; k < 256; ++k) {
                    float wvv = iW2[j * 256 + k];
#pragma unroll
                    for (int rr = 0; rr < 8; ++rr) a8[rr] += I.h1[(rb * 8 + rr) * 257 + k] * wvv;
                }
#pragma unroll
                for (int rr = 0; rr < 8; ++rr) I.h2[(rb * 8 + rr) * 257 + j] = sp_f(a8[rr]);
            }
        }
        __syncthreads();
        {
            float bias = ib3[j];
            for (int rb = 0; rb < 4; ++rb) {
                float a8[8];
#pragma unroll
                for (int rr = 0; rr < 8; ++rr) a8[rr] = bias;
                for (int k = 0; k < 256; ++k) {
                    float wvv = iW3[j * 256 + k];
#pragma unroll
                    for (int rr = 0; rr < 8; ++rr) a8[rr] += I.h2[(rb * 8 + rr) * 257 + k] * wvv;
                }
#pragma unroll
                for (int rr = 0; rr < 8; ++rr) {   // publish h0 pre-split
                    float v = a8[rr];
                    unsigned short hi = f2bf(v);
                    sth(&hhA[(b0 + rb * 8 + rr) * 256 + j], hi);
                    sth(&hlA[(b0 + rb * 8 + rr) * 256 + j], f2bf(v - bf2f(hi)));
                }
            }
        }
    } else if (blk < 16) {
        const int idx = blk - 8;
        const float* src = (idx < 4) ? vW1 : vW2;
        unsigned short* dh = (idx < 4) ? w1th : w2th;
        unsigned short* dl = (idx < 4) ? w1tl : w2tl;
        const int part = idx & 3;
        for (int u = part * 2048 + tid; u < (part + 1) * 2048; u += 256)
            cast_w8n(src, dh, dl, u, 256);
    } else {
        for (long u = (long)(blk - 16) * 256 + tid; u < 9216L * 32; u += 240L * 256)
            cast_w8n(vW3, w3th, w3tl, u, 9216);
    }
    gbar(slots, 1);

    // init owned h sub-tile (exact path starts from hi+lo reconstruction, ~1e-5 rel)
    if (tid < 64) {
        int r = tid >> 2, sq = tid & 3;
        U64F2 a, b;
        a.u = ldg64(hhA + (b0c16 + r) * 256 + s0g + sq * 4);
        b.u = ldg64(hlA + (b0c16 + r) * 256 + s0g + sq * 4);
#pragma unroll
        for (int q = 0; q < 4; ++q) hloc[r * 16 + sq * 4 + q] = bf2f(a.s[q]) + bf2f(b.s[q]);
    }

    // ================= main scan: one chunk-local barrier per step =================
    int lgen = 0;
    for (int t = 0; t < Tt; ++t) {
        GScr& G = S.g;
        const unsigned short* hhs = (t & 1) ? hhB : hhA;
        const unsigned short* hls = (t & 1) ? hlB : hlA;
        unsigned short* hhd = (t & 1) ? hhA : hhB;
        unsigned short* hld = (t & 1) ? hlA : hlB;

        // ---- gather h(t) [16 rows x 256] hi/lo into LDS (coalesced u64 copies) ----
        for (int u = tid; u < 1024; u += 256) {
            int r = u >> 6, c4 = (u & 63) * 4;
            *(unsigned long long*)(void*)&G.hh[r * 264 + c4] = ldg64(hhs + (b0c16 + r) * 256 + c4);
            *(unsigned long long*)(void*)&G.hl[r * 264 + c4] = ldg64(hls + (b0c16 + r) * 256 + c4);
        }
        // ---- logsigs slice [16 x 36] ----
        for (int i = tid; i < 16 * Ll; i += 256) {
            int r = i / Ll, l = i - r * Ll;
            G.lss[i] = logsigs[((long)(b0c16 + r) * Tt + t) * Ll + l];
        }
        __syncthreads();

        // ---- readout partials for row b0c16+sl (local row sl) ----
        if (lane < OUTd) {
            const int o = lane;
            float acc = 0.f;
            const short* ph = &G.hh[sl * 264 + wv * 64];
            const short* pl = &G.hl[sl * 264 + wv * 64];
            const float* wp = roW + o * 256 + wv * 64;
            for (int s = 0; s < 64; s += 8) {
                short8 vh = *(const short8*)(const void*)(ph + s);
                short8 vl = *(const short8*)(const void*)(pl + s);
                f32x4 w0 = *(const f32x4*)(wp + s);
                f32x4 w1 = *(const f32x4*)(wp + s + 4);
#pragma unroll
                for (int q = 0; q < 4; ++q) {
                    acc += (bf2f((unsigned short)vh[q]) + bf2f((unsigned short)vl[q])) * w0[q];
                    acc += (bf2f((unsigned short)vh[q + 4]) + bf2f((unsigned short)vl[q + 4])) * w1[q];
                }
            }
            rtmp[wv * 10 + o] = acc;
        }

        // ---- stage 1: z1 = sp(h W1^T) ----
        MLP_STAGE16(G.hh, G.hl, w1th, w1tl, vb1, G.z1h, G.z1l);
        __syncthreads();

        if (tid < OUTd)
            out[((long)(b0c16 + sl) * 513 + t) * OUTd + tid] =
                rob[tid] + rtmp[tid] + rtmp[10 + tid] + rtmp[20 + tid] + rtmp[30 + tid];

        // ---- stage 2: z2 = sp(z1 W2^T) ----
        MLP_STAGE16(G.z1h, G.z1l, w2th, w2tl, vb2, G.z2h, G.z2l);
        __syncthreads();

        // ---- W3 GEMM: m-pre = z2 @ W3slice^T  (B direct from global, L2-resident) ----
        {
            f32x4 acc[9];
#pragma unroll
            for (int nt = 0; nt < 9; ++nt) acc[nt] = zero4;
            for (int kk = 0; kk < 8; ++kk) {
                short8 ah = *(const short8*)(const void*)&G.z2h[l15 * 264 + kk * 32 + quad * 8];
                short8 al = *(const short8*)(const void*)&G.z2l[l15 * 264 + kk * 32 + quad * 8];
#pragma unroll
                for (int nt = 0; nt < 9; ++nt) {
                    long n = (long)n0g + wv * 144 + nt * 16 + l15;
                    long bo = ((long)kk * 9216 + n) * 32 + quad * 8;
                    short8 bh = *(const short8*)(const void*)(w3th + bo);
                    short8 bl = *(const short8*)(const void*)(w3tl + bo);
                    acc[nt] = __builtin_amdgcn_mfma_f32_16x16x32_bf16(ah, bh, acc[nt], 0, 0, 0);
                    acc[nt] = __builtin_amdgcn_mfma_f32_16x16x32_bf16(ah, bl, acc[nt], 0, 0, 0);
                    acc[nt] = __builtin_amdgcn_mfma_f32_16x16x32_bf16(al, bh, acc[nt], 0, 0, 0);
                }
            }
            // tanh epilogue -> ml
#pragma unroll
            for (int nt = 0; nt < 9; ++nt) {
                int nloc = wv * 144 + nt * 16 + l15;
                float bias = vb3[n0g + nloc];
#pragma unroll
                for (int r = 0; r < 4; ++r) {
                    int row = quad * 4 + r;
                    G.ml[row * 584 + nloc] = tanh_f(acc[nt][r] + bias);
                }
            }
        }
        __syncthreads();

        // ---- l-contraction: thread (r, s) owns h[r][s0g+s]: hloc += dot36 ----
        {
            int r = tid >> 4, sL = tid & 15;
            const f32x4* mp = (const f32x4*)(const void*)&G.ml[r * 584 + sL * 36];
            const f32x4* lp = (const f32x4*)(const void*)&G.lss[r * 36];
            float a = 0.f;
#pragma unroll
            for (int q = 0; q < 9; ++q) {
                f32x4 m4 = mp[q], l4 = lp[q];
                a += m4[0] * l4[0] + m4[1] * l4[1] + m4[2] * l4[2] + m4[3] * l4[3];
            }
            hloc[tid] += a;
        }
        __syncthreads();

        // ---- publish owned h sub-tile pre-split to the other buffer ----
        if (tid < 64) {
            int r = tid >> 2, sq = tid & 3;
            U64F2 H, L;
#pragma unroll
            for (int q = 0; q < 4; ++q) {
                float v = hloc[r * 16 + sq * 4 + q];
                unsigned short hi = f2bf(v);
                H.s[q] = hi;
                L.s[q] = f2bf(v - bf2f(hi));
            }
            stg64(hhd + (b0c16 + r) * 256 + s0g + sq * 4, H.u);
            stg64(hld + (b0c16 + r) * 256 + s0g + sq * 4, L.u);
        }
        cbar(cb, ++lgen);
    }

    // ---- final readout out[:, 512, :]: row b0c16+sl, h(512) in A buffers (Tt even) ----
    {
        float* fb = S.g.ml;   // reuse as f32 row buffer
        if (tid < 64) {
            U64F2 a, b;
            a.u = ldg64(hhA + (long)(b0c16 + sl) * 256 + tid * 4);
            b.u = ldg64(hlA + (long)(b0c16 + sl) * 256 + tid * 4);
#pragma unroll
            for (int q = 0; q < 4; ++q) fb[tid * 4 + q] = bf2f(a.s[q]) + bf2f(b.s[q]);
        }
        __syncthreads();
        if (tid < OUTd) {
            float acc = rob[tid];
            const float* wp = roW + tid * 256;
            for (int s = 0; s < 256; s += 4) {
                f32x4 hv = *(const f32x4*)(fb + s);
                f32x4 w4 = *(const f32x4*)(wp + s);
                acc += hv[0] * w4[0] + hv[1] * w4[1] + hv[2] * w4[2] + hv[3] * w4[3];
            }
            out[((long)(b0c16 + sl) * 513 + Tt) * OUTd + tid] = acc;
        }
    }
}

extern "C" void kernel_launch(void* const* d_in, const int* in_sizes, int n_in,
                              void* d_out, int out_size, void* d_ws, size_t ws_size,
                              hipStream_t stream) {
    const float* x0      = (const float*)d_in[0];
    const float* logsigs = (const float*)d_in[1];
    const float* iW1 = (const float*)d_in[2];
    const float* ib1 = (const float*)d_in[3];
    const float* iW2 = (const float*)d_in[4];
    const float* ib2 = (const float*)d_in[5];
    const float* iW3 = (const float*)d_in[6];
    const float* ib3 = (const float*)d_in[7];
    const float* vW1 = (const float*)d_in[8];
    const float* vb1 = (const float*)d_in[9];
    const float* vW2 = (const float*)d_in[10];
    const float* vb2 = (const float*)d_in[11];
    const float* vW3 = (const float*)d_in[12];
    const float* vb3 = (const float*)d_in[13];
    const float* roW = (const float*)d_in[14];
    const float* rob = (const float*)d_in[15];
    float* out = (float*)d_out;

    char* p = (char*)d_ws;
    unsigned short* hhA  = (unsigned short*)p;                // 131072 B
    unsigned short* hlA  = (unsigned short*)(p + 131072);     // 131072 B
    unsigned short* hhB  = (unsigned short*)(p + 262144);     // 131072 B
    unsigned short* hlB  = (unsigned short*)(p + 393216);     // 131072 B
    unsigned short* w1th = (unsigned short*)(p + 524288);     // 131072 B
    unsigned short* w1tl = (unsigned short*)(p + 655360);     // 131072 B
    unsigned short* w2th = (unsigned short*)(p + 786432);     // 131072 B
    unsigned short* w2tl = (unsigned short*)(p + 917504);     // 131072 B
    unsigned short* w3th = (unsigned short*)(p + 1048576);    // 4718592 B
    unsigned short* w3tl = (unsigned short*)(p + 5767168);    // 4718592 B
    int* slots           = (int*)(p + 10485760);              // barriers: gbar [0,512], cbar [1024,1504]

    hipMemsetAsync(slots, 0, 8192, stream);
    rde_fused4<<<dim3(256), dim3(256), 0, stream>>>(
        x0, logsigs, iW1, ib1, iW2, ib2, iW3, ib3,
        vW1, vb1, vW2, vb2, vW3, vb3, roW, rob, out,
        hhA, hlA, hhB, hlB, w1th, w1tl, w2th, w2tl, w3th, w3tl, slots);
}